// Round 1
// baseline (312.269 us; speedup 1.0000x reference)
//
#include <hip/hip_runtime.h>
#include <math.h>

// Problem constants
#define A_N   8400
#define BS    32
#define NGT   64
#define NC    80
#define TK    13
#define EPSF  1e-9f

// Output layout (floats), concatenated in reference return order
#define OFF_LB 0
#define OFF_BB (BS * A_N)                      // 268800
#define OFF_SC (OFF_BB + BS * A_N * 4)         // 1344000
#define OFF_FG (OFF_SC + BS * A_N * NC)        // 22848000
// total out = 23116800 floats

// Workspace layout (byte offsets)
#define WS_FLAG   0
#define WS_TOPK   256                          // 2048*13*4 = 106496
#define WS_CNT    106752                       // 268800*4
#define WS_MINJ   (WS_CNT  + BS * A_N * 4)
#define WS_INFO   (WS_MINJ + BS * A_N * 4)
#define WS_ALIGN  (WS_INFO + BS * A_N * 4)
#define WS_POSA   (WS_ALIGN + BS * A_N * 4)
#define WS_POSO   (WS_POSA + BS * NGT * 4)
// end = WS_POSO + 8192  ~= 4.42 MB

__device__ __forceinline__ float iou_f(float g0, float g1, float g2, float g3,
                                       float p0, float p1, float p2, float p3) {
    // exact op order of the reference:
    // overlap = max(rb-lt,0).prod ; union = area1 + area2 - overlap + eps
    float ltx = fmaxf(g0, p0), lty = fmaxf(g1, p1);
    float rbx = fminf(g2, p2), rby = fminf(g3, p3);
    float ov  = fmaxf(rbx - ltx, 0.f) * fmaxf(rby - lty, 0.f);
    float a1  = fmaxf(g2 - g0, 0.f) * fmaxf(g3 - g1, 0.f);
    float a2  = fmaxf(p2 - p0, 0.f) * fmaxf(p3 - p1, 0.f);
    return ov / (a1 + a2 - ov + EPSF);
}

__device__ __forceinline__ int get_gl(const int* g, int flag64, int i) {
    return flag64 ? g[2 * i] : g[i];
}

// ---------------- Kernel 0: init counters + detect gt_labels stride ----------
__global__ __launch_bounds__(256) void k_init(int* cnt, int* minj,
                                              unsigned int* posA, unsigned int* posO,
                                              int* flag, const int* gl_raw) {
    int i = blockIdx.x * 256 + threadIdx.x;
    if (i < BS * A_N) { cnt[i] = 0; minj[i] = 1 << 30; }
    if (i < BS * NGT) { posA[i] = 0u; posO[i] = 0u; }
    if (i == 0) {
        // int64 little-endian => high words (odd int32 indices) are all 0.
        // int32 => odd indices are labels; 64 consecutive zeros is impossible.
        int f = 1;
        for (int k = 0; k < 64; k++) {
            if (gl_raw[2 * k + 1] != 0) { f = 0; break; }
        }
        *flag = f;
    }
}

// ---------------- Kernel 1: per-(b,j) metric + exact top-13 ------------------
__global__ __launch_bounds__(256) void k_topk(
    const float* __restrict__ pd_scores, const float* __restrict__ pd_bboxes,
    const float* __restrict__ anc, const int* __restrict__ gl_raw,
    const float* __restrict__ gt_bboxes, const float* __restrict__ mask_gt,
    const int* __restrict__ flag, int* __restrict__ topk_out) {
    __shared__ float smet[A_N];
    __shared__ float redV[256];
    __shared__ int   redI[256];
    __shared__ int   winners[TK];

    int bj  = blockIdx.x;          // b*64 + j
    int b   = bj >> 6;
    int tid = threadIdx.x;

    float mg = mask_gt[bj];
    if (mg == 0.f) {               // topk_idxs forced to 0 -> counts[0]=13>1 -> all masked out
        if (tid < TK) topk_out[bj * TK + tid] = -1;
        return;
    }
    int f64 = *flag;
    int lbl = get_gl(gl_raw, f64, bj);
    float g0 = gt_bboxes[bj * 4 + 0], g1 = gt_bboxes[bj * 4 + 1];
    float g2 = gt_bboxes[bj * 4 + 2], g3 = gt_bboxes[bj * 4 + 3];

    const float4* pb = (const float4*)(pd_bboxes + (size_t)b * A_N * 4);
    const float2* ap = (const float2*)anc;
    const float*  sc = pd_scores + (size_t)b * A_N * NC + lbl;

    for (int a = tid; a < A_N; a += 256) {
        float2 an = ap[a];
        float d = fminf(fminf(an.x - g0, an.y - g1), fminf(g2 - an.x, g3 - an.y));
        float m = 0.f;
        if (d > EPSF) {
            float4 p = pb[a];
            float ov = iou_f(g0, g1, g2, g3, p.x, p.y, p.z, p.w);
            if (ov > 0.f) {
                float s = sc[(size_t)a * NC];   // sparse gather (~2% of anchors)
                m = s * powf(ov, 6.0f);         // score^1 * ov^6, accurate pow
            }
        }
        smet[a] = m;
    }
    __syncthreads();

    // 13 rounds of block argmax with (value desc, index asc) tie-break — matches lax.top_k
    for (int r = 0; r < TK; r++) {
        float bv = -1.f; int bi = 0;
        for (int a = tid; a < A_N; a += 256) {
            float v = smet[a];
            if (v > bv) { bv = v; bi = a; }     // ascending scan -> lowest idx per thread
        }
        redV[tid] = bv; redI[tid] = bi;
        __syncthreads();
        for (int s = 128; s > 0; s >>= 1) {
            if (tid < s) {
                float v2 = redV[tid + s]; int i2 = redI[tid + s];
                if (v2 > redV[tid] || (v2 == redV[tid] && i2 < redI[tid])) {
                    redV[tid] = v2; redI[tid] = i2;
                }
            }
            __syncthreads();
        }
        if (tid == 0) { winners[r] = redI[0]; smet[redI[0]] = -1.f; }
        __syncthreads();
    }

    if (tid < TK) {
        int idx = winners[tid];
        float2 an = ap[idx];
        float d = fminf(fminf(an.x - g0, an.y - g1), fminf(g2 - an.x, g3 - an.y));
        // position survives iff mask_in_gts at the selected anchor
        topk_out[bj * TK + tid] = (d > EPSF) ? idx : -1;
    }
}

// ---------------- Kernel 2: scatter topk lists into per-anchor cnt/minj ------
__global__ __launch_bounds__(256) void k_scatter(const int* __restrict__ topk,
                                                 int* __restrict__ cnt,
                                                 int* __restrict__ minj) {
    int i = blockIdx.x * 256 + threadIdx.x;
    if (i >= BS * NGT * TK) return;
    int idx = topk[i];
    if (idx < 0) return;
    int bj = i / TK;
    int b = bj >> 6, j = bj & 63;
    atomicAdd(&cnt[b * A_N + idx], 1);
    atomicMin(&minj[b * A_N + idx], j);
}

// ---------------- Kernel 3: per-anchor assignment + labels/bboxes/fg ---------
__global__ __launch_bounds__(256) void k_assign(
    const float* __restrict__ pd_scores, const float* __restrict__ pd_bboxes,
    const float* __restrict__ gt_bboxes, const int* __restrict__ gl_raw,
    const float* __restrict__ mask_gt, const int* __restrict__ flag,
    const int* __restrict__ cnt, const int* __restrict__ minj,
    int* __restrict__ info, float* __restrict__ alignArr,
    unsigned int* posA, unsigned int* posO, float* __restrict__ out) {
    int i = blockIdx.x * 256 + threadIdx.x;
    if (i >= BS * A_N) return;
    int b = i / A_N;
    int c = cnt[i];
    int f64 = *flag;

    float4 p = ((const float4*)pd_bboxes)[i];
    int jstar = 0;
    if (c == 1) {
        jstar = minj[i];
    } else if (c > 1) {
        // mask_multi: replace with one_hot(argmax_j overlaps) — first-max tie like np.argmax
        float bv = -1.f; int bj_ = 0;
        const float4* gb = (const float4*)(gt_bboxes + (size_t)b * NGT * 4);
        for (int j = 0; j < NGT; j++) {
            float4 g = gb[j];
            float ov = iou_f(g.x, g.y, g.z, g.w, p.x, p.y, p.z, p.w);
            if (ov > bv) { bv = ov; bj_ = j; }
        }
        jstar = bj_;
    }

    int lbl = get_gl(gl_raw, f64, b * NGT + jstar);
    if (lbl < 0) lbl = 0;

    out[OFF_LB + i] = (float)lbl;                       // take_along_axis is unconditional
    float4 g = ((const float4*)gt_bboxes)[b * NGT + jstar];
    ((float4*)(out + OFF_BB))[i] = g;

    int fg = (c > 0) ? 1 : 0;
    out[OFF_FG + i] = (float)fg;

    float al = 0.f;
    if (fg) {
        float ov = iou_f(g.x, g.y, g.z, g.w, p.x, p.y, p.z, p.w);
        float s  = pd_scores[(size_t)i * NC + lbl];
        al = s * powf(ov, 6.0f);
        // non-negative floats: int-punned atomicMax == float max
        atomicMax((int*)&posA[b * NGT + jstar], __float_as_int(al));
        atomicMax((int*)&posO[b * NGT + jstar], __float_as_int(ov));
    }
    alignArr[i] = al;
    info[i] = jstar | (lbl << 8) | (fg << 16);
}

// ---------------- Kernel 4: write the 86 MB target_scores (coalesced f4) -----
__global__ __launch_bounds__(256) void k_scores(
    const int* __restrict__ info, const float* __restrict__ alignArr,
    const unsigned int* __restrict__ posA, const unsigned int* __restrict__ posO,
    float* __restrict__ out) {
    int t = blockIdx.x * 256 + threadIdx.x;
    const int TOT = BS * A_N * (NC / 4);   // 5,376,000 float4 stores
    if (t >= TOT) return;
    int anchor = t / (NC / 4);
    int q = t - anchor * (NC / 4);
    int inf = info[anchor];
    float4 v = make_float4(0.f, 0.f, 0.f, 0.f);
    if (inf & (1 << 16)) {
        int lbl = (inf >> 8) & 255;
        int c0 = q * 4;
        if (lbl >= c0 && lbl < c0 + 4) {
            int jstar = inf & 255;
            int b = anchor / A_N;
            float pa = __int_as_float((int)posA[b * NGT + jstar]);
            float po = __int_as_float((int)posO[b * NGT + jstar]);
            float norm = alignArr[anchor] * po / (pa + EPSF);
            ((float*)&v)[lbl - c0] = norm;
        }
    }
    ((float4*)(out + OFF_SC))[t] = v;
}

extern "C" void kernel_launch(void* const* d_in, const int* in_sizes, int n_in,
                              void* d_out, int out_size, void* d_ws, size_t ws_size,
                              hipStream_t stream) {
    const float* pd_scores = (const float*)d_in[0];
    const float* pd_bboxes = (const float*)d_in[1];
    const float* anc       = (const float*)d_in[2];
    const int*   gl_raw    = (const int*)d_in[3];
    const float* gt_bboxes = (const float*)d_in[4];
    const float* mask_gt   = (const float*)d_in[5];
    float* out = (float*)d_out;

    char* ws = (char*)d_ws;
    int*          flag  = (int*)(ws + WS_FLAG);
    int*          topk  = (int*)(ws + WS_TOPK);
    int*          cnt   = (int*)(ws + WS_CNT);
    int*          minj  = (int*)(ws + WS_MINJ);
    int*          info  = (int*)(ws + WS_INFO);
    float*        alignArr = (float*)(ws + WS_ALIGN);
    unsigned int* posA  = (unsigned int*)(ws + WS_POSA);
    unsigned int* posO  = (unsigned int*)(ws + WS_POSO);

    k_init<<<(BS * A_N + 255) / 256, 256, 0, stream>>>(cnt, minj, posA, posO, flag, gl_raw);
    k_topk<<<BS * NGT, 256, 0, stream>>>(pd_scores, pd_bboxes, anc, gl_raw,
                                         gt_bboxes, mask_gt, flag, topk);
    k_scatter<<<(BS * NGT * TK + 255) / 256, 256, 0, stream>>>(topk, cnt, minj);
    k_assign<<<(BS * A_N + 255) / 256, 256, 0, stream>>>(pd_scores, pd_bboxes, gt_bboxes,
                                                         gl_raw, mask_gt, flag, cnt, minj,
                                                         info, alignArr, posA, posO, out);
    k_scores<<<(BS * A_N * (NC / 4) + 255) / 256, 256, 0, stream>>>(info, alignArr,
                                                                    posA, posO, out);
}

// Round 2
// 267.479 us; speedup vs baseline: 1.1675x; 1.1675x over previous
//
#include <hip/hip_runtime.h>
#include <math.h>

// Problem constants
#define A_N   8400
#define BS    32
#define NGT   64
#define NC    80
#define TK    13
#define EPSF  1e-9f
#define CAP   1024          // max candidates per (b,gt); in-box count bounded ~640 for wh<=160

// Output layout (floats), concatenated in reference return order
#define OFF_LB 0
#define OFF_BB (BS * A_N)                      // 268800
#define OFF_SC (OFF_BB + BS * A_N * 4)         // 1344000
#define OFF_FG (OFF_SC + BS * A_N * NC)        // 22848000

// Workspace layout (byte offsets, all 256-aligned)
#define WS_FLAG   0
#define WS_CNT    256
#define WS_MINJ   (WS_CNT   + BS * A_N * 4)    // +1,075,200
#define WS_INFO   (WS_MINJ  + BS * A_N * 4)
#define WS_ALIGN  (WS_INFO  + BS * A_N * 4)
#define WS_POSA   (WS_ALIGN + BS * A_N * 4)
#define WS_POSO   (WS_POSA  + BS * NGT * 4)    // +8192
#define WS_CNT2   (WS_POSO  + BS * NGT * 4)
#define WS_CAND   (WS_CNT2  + BS * NGT * 4)
// cand: 2048 * CAP * 8 = 16.78 MB ; total ~= 21.1 MB

__device__ __forceinline__ float iou_f(float g0, float g1, float g2, float g3,
                                       float p0, float p1, float p2, float p3) {
    float ltx = fmaxf(g0, p0), lty = fmaxf(g1, p1);
    float rbx = fminf(g2, p2), rby = fminf(g3, p3);
    float ov  = fmaxf(rbx - ltx, 0.f) * fmaxf(rby - lty, 0.f);
    float a1  = fmaxf(g2 - g0, 0.f) * fmaxf(g3 - g1, 0.f);
    float a2  = fmaxf(p2 - p0, 0.f) * fmaxf(p3 - p1, 0.f);
    return ov / (a1 + a2 - ov + EPSF);
}

__device__ __forceinline__ int get_gl(const int* g, int flag64, int i) {
    return flag64 ? g[2 * i] : g[i];
}

__device__ __forceinline__ unsigned long long shfl_xor_u64(unsigned long long x, int m) {
    int lo = __shfl_xor((int)(unsigned int)(x & 0xFFFFFFFFull), m, 64);
    int hi = __shfl_xor((int)(unsigned int)(x >> 32), m, 64);
    return ((unsigned long long)(unsigned int)hi << 32) | (unsigned int)lo;
}

// ---------------- Kernel 0: init counters + detect gt_labels stride ----------
__global__ __launch_bounds__(256) void k_init(int* cnt, int* minj,
                                              unsigned int* posA, unsigned int* posO,
                                              int* cnt2, int* flag, const int* gl_raw) {
    int i = blockIdx.x * 256 + threadIdx.x;
    if (i < BS * A_N) { cnt[i] = 0; minj[i] = 1 << 30; }
    if (i < BS * NGT) { posA[i] = 0u; posO[i] = 0u; cnt2[i] = 0; }
    if (i == 0) {
        int f = 1;
        for (int k = 0; k < 64; k++) {
            if (gl_raw[2 * k + 1] != 0) { f = 0; break; }
        }
        *flag = f;
    }
}

// ---------------- Kernel 1: dense in-box sweep -> per-(b,gt) candidate lists -
// grid: 32 batches x 33 anchor tiles, one thread per anchor.
__global__ __launch_bounds__(256) void k_cand(
    const float* __restrict__ pd_scores, const float* __restrict__ pd_bboxes,
    const float* __restrict__ anc, const int* __restrict__ gl_raw,
    const float* __restrict__ gt_bboxes, const float* __restrict__ mask_gt,
    const int* __restrict__ flag,
    int* __restrict__ cnt2, unsigned long long* __restrict__ cand) {
    __shared__ float4 sgt[NGT];
    __shared__ int    slbl[NGT];
    __shared__ int    smask[NGT];

    int b    = blockIdx.x / 33;
    int tile = blockIdx.x % 33;
    int tid  = threadIdx.x;
    int a    = tile * 256 + tid;

    if (tid < NGT) {
        sgt[tid]   = ((const float4*)gt_bboxes)[b * NGT + tid];
        slbl[tid]  = get_gl(gl_raw, *flag, b * NGT + tid);
        smask[tid] = (mask_gt[b * NGT + tid] != 0.f);
    }
    __syncthreads();
    if (a >= A_N) return;

    float2 an = ((const float2*)anc)[a];
    float4 p  = ((const float4*)pd_bboxes)[(size_t)b * A_N + a];
    const float* sc = pd_scores + (size_t)b * A_N * NC + (size_t)a * NC;

    for (int j = 0; j < NGT; j++) {
        if (!smask[j]) continue;                       // block-uniform branch
        float4 g = sgt[j];
        float d = fminf(fminf(an.x - g.x, an.y - g.y),
                        fminf(g.z - an.x, g.w - an.y));
        if (d > EPSF) {
            float iou = iou_f(g.x, g.y, g.z, g.w, p.x, p.y, p.z, p.w);
            float m = 0.f;
            if (iou > 0.f) {
                float s = sc[slbl[j]];
                m = s * powf(iou, 6.0f);               // identical op order to R1 (absmax 0.0)
            }
            int bj = b * NGT + j;
            int slot = atomicAdd(&cnt2[bj], 1);
            if (slot < CAP) {
                unsigned long long key =
                    ((unsigned long long)__float_as_uint(m) << 32) |
                    (unsigned int)(~(unsigned int)a);  // (metric desc, anchor asc) under max
                cand[(size_t)bj * CAP + slot] = key;
            }
        }
    }
}

// ---------------- Kernel 2: per-(b,gt) wave top-13 + scatter -----------------
// grid 512 x 256: one 64-lane wave per (b,j). No LDS, no barriers.
__global__ __launch_bounds__(256) void k_pick(
    const int* __restrict__ cnt2, const unsigned long long* __restrict__ cand,
    int* __restrict__ cnt, int* __restrict__ minj) {
    int lane = threadIdx.x & 63;
    int wave = threadIdx.x >> 6;
    int bj = blockIdx.x * 4 + wave;
    int b = bj >> 6, j = bj & 63;

    int n = min(cnt2[bj], CAP);
    if (n == 0) return;                                // wave-uniform

    const unsigned long long* L = cand + (size_t)bj * CAP;
    unsigned long long k0[CAP / 64];
    #pragma unroll
    for (int t = 0; t < CAP / 64; t++) {
        int i = t * 64 + lane;
        k0[t] = (i < n) ? L[i] : 0ULL;                 // 0 = empty (real keys are nonzero)
    }

    unsigned int wanchor[TK];
    int P = 0;
    #pragma unroll
    for (int r = 0; r < TK; r++) {
        unsigned long long best = 0;
        #pragma unroll
        for (int t = 0; t < CAP / 64; t++) best = (k0[t] > best) ? k0[t] : best;
        for (int s = 1; s < 64; s <<= 1) {
            unsigned long long o = shfl_xor_u64(best, s);
            if (o > best) best = o;
        }
        if (!(best >> 32)) break;                      // out of positive metrics
        unsigned int aw = ~(unsigned int)(best & 0xFFFFFFFFull);
        wanchor[r] = aw;
        if (lane == 0) {
            atomicAdd(&cnt[b * A_N + (int)aw], 1);
            atomicMin(&minj[b * A_N + (int)aw], j);
        }
        #pragma unroll
        for (int t = 0; t < CAP / 64; t++) if (k0[t] == best) k0[t] = 0;
        P++;
    }

    // Fillers: lax.top_k back-fills (13-P) lowest-index zero-metric anchors of the
    // FULL 8400 array; only in-box ones (all present as zero-metric candidates)
    // survive mask_in_gts. a is a filler iff a - |{positive anchors < a}| < 13-P.
    if (P < TK) {
        int K = TK - P;
        #pragma unroll
        for (int t = 0; t < CAP / 64; t++) {
            unsigned long long key = k0[t];
            if (key != 0 && !(key >> 32)) {
                unsigned int a0 = ~(unsigned int)(key & 0xFFFFFFFFull);
                int off = 0;
                #pragma unroll
                for (int r = 0; r < TK; r++)
                    if (r < P && wanchor[r] < a0) off++;
                if ((int)a0 < K + off) {
                    atomicAdd(&cnt[b * A_N + (int)a0], 1);
                    atomicMin(&minj[b * A_N + (int)a0], j);
                }
            }
        }
    }
}

// ---------------- Kernel 3: per-anchor assignment + labels/bboxes/fg ---------
__global__ __launch_bounds__(256) void k_assign(
    const float* __restrict__ pd_scores, const float* __restrict__ pd_bboxes,
    const float* __restrict__ gt_bboxes, const int* __restrict__ gl_raw,
    const int* __restrict__ flag,
    const int* __restrict__ cnt, const int* __restrict__ minj,
    int* __restrict__ info, float* __restrict__ alignArr,
    unsigned int* posA, unsigned int* posO, float* __restrict__ out) {
    int i = blockIdx.x * 256 + threadIdx.x;
    if (i >= BS * A_N) return;
    int b = i / A_N;
    int c = cnt[i];
    int f64 = *flag;

    float4 p = ((const float4*)pd_bboxes)[i];
    int jstar = 0;
    if (c == 1) {
        jstar = minj[i];
    } else if (c > 1) {
        float bv = -1.f; int bj_ = 0;
        const float4* gb = (const float4*)(gt_bboxes + (size_t)b * NGT * 4);
        for (int j = 0; j < NGT; j++) {
            float4 g = gb[j];
            float ov = iou_f(g.x, g.y, g.z, g.w, p.x, p.y, p.z, p.w);
            if (ov > bv) { bv = ov; bj_ = j; }
        }
        jstar = bj_;
    }

    int lbl = get_gl(gl_raw, f64, b * NGT + jstar);
    if (lbl < 0) lbl = 0;

    out[OFF_LB + i] = (float)lbl;
    float4 g = ((const float4*)gt_bboxes)[b * NGT + jstar];
    ((float4*)(out + OFF_BB))[i] = g;

    int fg = (c > 0) ? 1 : 0;
    out[OFF_FG + i] = (float)fg;

    float al = 0.f;
    if (fg) {
        float ov = iou_f(g.x, g.y, g.z, g.w, p.x, p.y, p.z, p.w);
        float s  = pd_scores[(size_t)i * NC + lbl];
        al = s * powf(ov, 6.0f);
        atomicMax((int*)&posA[b * NGT + jstar], __float_as_int(al));
        atomicMax((int*)&posO[b * NGT + jstar], __float_as_int(ov));
    }
    alignArr[i] = al;
    info[i] = jstar | (lbl << 8) | (fg << 16);
}

// ---------------- Kernel 4: write the 86 MB target_scores (coalesced f4) -----
__global__ __launch_bounds__(256) void k_scores(
    const int* __restrict__ info, const float* __restrict__ alignArr,
    const unsigned int* __restrict__ posA, const unsigned int* __restrict__ posO,
    float* __restrict__ out) {
    int t = blockIdx.x * 256 + threadIdx.x;
    const int TOT = BS * A_N * (NC / 4);
    if (t >= TOT) return;
    int anchor = t / (NC / 4);
    int q = t - anchor * (NC / 4);
    int inf = info[anchor];
    float4 v = make_float4(0.f, 0.f, 0.f, 0.f);
    if (inf & (1 << 16)) {
        int lbl = (inf >> 8) & 255;
        int c0 = q * 4;
        if (lbl >= c0 && lbl < c0 + 4) {
            int jstar = inf & 255;
            int b = anchor / A_N;
            float pa = __int_as_float((int)posA[b * NGT + jstar]);
            float po = __int_as_float((int)posO[b * NGT + jstar]);
            float norm = alignArr[anchor] * po / (pa + EPSF);
            ((float*)&v)[lbl - c0] = norm;
        }
    }
    ((float4*)(out + OFF_SC))[t] = v;
}

extern "C" void kernel_launch(void* const* d_in, const int* in_sizes, int n_in,
                              void* d_out, int out_size, void* d_ws, size_t ws_size,
                              hipStream_t stream) {
    const float* pd_scores = (const float*)d_in[0];
    const float* pd_bboxes = (const float*)d_in[1];
    const float* anc       = (const float*)d_in[2];
    const int*   gl_raw    = (const int*)d_in[3];
    const float* gt_bboxes = (const float*)d_in[4];
    const float* mask_gt   = (const float*)d_in[5];
    float* out = (float*)d_out;

    char* ws = (char*)d_ws;
    int*                flag     = (int*)(ws + WS_FLAG);
    int*                cnt      = (int*)(ws + WS_CNT);
    int*                minj     = (int*)(ws + WS_MINJ);
    int*                info     = (int*)(ws + WS_INFO);
    float*              alignArr = (float*)(ws + WS_ALIGN);
    unsigned int*       posA     = (unsigned int*)(ws + WS_POSA);
    unsigned int*       posO     = (unsigned int*)(ws + WS_POSO);
    int*                cnt2     = (int*)(ws + WS_CNT2);
    unsigned long long* cand     = (unsigned long long*)(ws + WS_CAND);

    k_init<<<(BS * A_N + 255) / 256, 256, 0, stream>>>(cnt, minj, posA, posO, cnt2, flag, gl_raw);
    k_cand<<<BS * 33, 256, 0, stream>>>(pd_scores, pd_bboxes, anc, gl_raw,
                                        gt_bboxes, mask_gt, flag, cnt2, cand);
    k_pick<<<BS * NGT / 4, 256, 0, stream>>>(cnt2, cand, cnt, minj);
    k_assign<<<(BS * A_N + 255) / 256, 256, 0, stream>>>(pd_scores, pd_bboxes, gt_bboxes,
                                                         gl_raw, flag, cnt, minj,
                                                         info, alignArr, posA, posO, out);
    k_scores<<<(BS * A_N * (NC / 4) + 255) / 256, 256, 0, stream>>>(info, alignArr,
                                                                    posA, posO, out);
}

// Round 4
// 217.328 us; speedup vs baseline: 1.4369x; 1.2308x over previous
//
#include <hip/hip_runtime.h>
#include <math.h>

// Problem constants
#define A_N   8400
#define BS    32
#define NGT   64
#define NC    80
#define TK    13
#define EPSF  1e-9f
#define CAP   1024          // dense per-(b,gt) candidate list capacity
#define JG    32            // gts per k_cand block (64 split in 2 groups)
#define NJG   2
#define NTILE 33            // ceil(8400/256)
#define PCAP  64            // LDS pool capacity per (block, gt)

typedef float nt4 __attribute__((ext_vector_type(4)));   // native vec for nontemporal store

// Output layout (floats), concatenated in reference return order
#define OFF_LB 0
#define OFF_BB (BS * A_N)
#define OFF_SC (OFF_BB + BS * A_N * 4)
#define OFF_FG (OFF_SC + BS * A_N * NC)

// Workspace layout (byte offsets, all 256-aligned)
#define WS_FLAG   0
#define WS_CNT    256
#define WS_MINJ   (WS_CNT   + BS * A_N * 4)
#define WS_INFO   (WS_MINJ  + BS * A_N * 4)
#define WS_ALIGN  (WS_INFO  + BS * A_N * 4)
#define WS_POSA   (WS_ALIGN + BS * A_N * 4)
#define WS_POSO   (WS_POSA  + BS * NGT * 4)
#define WS_CNT2   (WS_POSO  + BS * NGT * 4)
#define WS_CAND   (WS_CNT2  + BS * NGT * 4)
// cand: 2048 * CAP * 8 = 16.78 MB ; total ~= 21.1 MB

__device__ __forceinline__ float iou_f(float g0, float g1, float g2, float g3,
                                       float p0, float p1, float p2, float p3) {
    float ltx = fmaxf(g0, p0), lty = fmaxf(g1, p1);
    float rbx = fminf(g2, p2), rby = fminf(g3, p3);
    float ov  = fmaxf(rbx - ltx, 0.f) * fmaxf(rby - lty, 0.f);
    float a1  = fmaxf(g2 - g0, 0.f) * fmaxf(g3 - g1, 0.f);
    float a2  = fmaxf(p2 - p0, 0.f) * fmaxf(p3 - p1, 0.f);
    return ov / (a1 + a2 - ov + EPSF);
}

__device__ __forceinline__ int get_gl(const int* g, int flag64, int i) {
    return flag64 ? g[2 * i] : g[i];
}

__device__ __forceinline__ unsigned long long shfl_xor_u64(unsigned long long x, int m) {
    int lo = __shfl_xor((int)(unsigned int)(x & 0xFFFFFFFFull), m, 64);
    int hi = __shfl_xor((int)(unsigned int)(x >> 32), m, 64);
    return ((unsigned long long)(unsigned int)hi << 32) | (unsigned int)lo;
}

// ---------------- Kernel 0: init counters + detect gt_labels stride ----------
__global__ __launch_bounds__(256) void k_init(int* cnt, int* minj,
                                              unsigned int* posA, unsigned int* posO,
                                              int* cnt2, int* flag, const int* gl_raw) {
    int i = blockIdx.x * 256 + threadIdx.x;
    if (i < BS * A_N) { cnt[i] = 0; minj[i] = 1 << 30; }
    if (i < BS * NGT) { posA[i] = 0u; posO[i] = 0u; cnt2[i] = 0; }
    if (i == 0) {
        int f = 1;
        for (int k = 0; k < 64; k++) {
            if (gl_raw[2 * k + 1] != 0) { f = 0; break; }
        }
        *flag = f;
    }
}

// ---------------- Kernel 1: dense in-box sweep -> per-(b,gt) candidate lists -
// grid: 32 batches x 33 anchor tiles x 2 gt-groups. LDS aggregation: hits land
// in per-(block,gt) LDS sub-lists via LDS atomics; ONE global atomicAdd per
// (block,gt) reserves a chunk; block flushes LDS->global. Overflow (>PCAP)
// falls back to per-lane direct global append (correct, just slower).
__global__ __launch_bounds__(256) void k_cand(
    const float* __restrict__ pd_scores, const float* __restrict__ pd_bboxes,
    const float* __restrict__ anc, const int* __restrict__ gl_raw,
    const float* __restrict__ gt_bboxes, const float* __restrict__ mask_gt,
    const int* __restrict__ flag,
    int* __restrict__ cnt2, unsigned long long* __restrict__ cand) {
    __shared__ float4 sgt[JG];
    __shared__ int    slbl[JG];
    __shared__ int    smask[JG];
    __shared__ int    cnt_lds[JG];
    __shared__ int    base_lds[JG];
    __shared__ unsigned long long pool[JG][PCAP];

    int bid  = blockIdx.x;
    int b    = bid / (NTILE * NJG);
    int rem  = bid % (NTILE * NJG);
    int tile = rem / NJG;
    int jg   = rem % NJG;
    int tid  = threadIdx.x;
    int a    = tile * 256 + tid;
    int jbase = b * NGT + jg * JG;

    if (tid < JG) {
        sgt[tid]   = ((const float4*)gt_bboxes)[jbase + tid];
        slbl[tid]  = get_gl(gl_raw, *flag, jbase + tid);
        smask[tid] = (mask_gt[jbase + tid] != 0.f);
        cnt_lds[tid] = 0;
    }
    __syncthreads();

    bool act = (a < A_N);
    float2 an = make_float2(0.f, 0.f);
    float4 p  = make_float4(0.f, 0.f, 0.f, 0.f);
    const float* sc = pd_scores;
    if (act) {
        an = ((const float2*)anc)[a];
        p  = ((const float4*)pd_bboxes)[(size_t)b * A_N + a];
        sc = pd_scores + (size_t)b * A_N * NC + (size_t)a * NC;
    }

    // Phase A: hit detection + LDS append
    for (int j = 0; j < JG; j++) {
        if (!smask[j]) continue;                       // block-uniform
        if (!act) continue;
        float4 g = sgt[j];
        float d = fminf(fminf(an.x - g.x, an.y - g.y),
                        fminf(g.z - an.x, g.w - an.y));
        if (d > EPSF) {
            float iou = iou_f(g.x, g.y, g.z, g.w, p.x, p.y, p.z, p.w);
            float m = 0.f;
            if (iou > 0.f) {
                float s = sc[slbl[j]];
                m = s * powf(iou, 6.0f);               // identical op order (absmax 0.0)
            }
            unsigned long long key =
                ((unsigned long long)__float_as_uint(m) << 32) |
                (unsigned int)(~(unsigned int)a);      // (metric desc, anchor asc) under max
            int slot = atomicAdd(&cnt_lds[j], 1);      // LDS atomic
            if (slot < PCAP) {
                pool[j][slot] = key;
            } else {                                   // rare overflow: direct global
                int gs = atomicAdd(&cnt2[jbase + j], 1);
                if (gs < CAP) cand[(size_t)(jbase + j) * CAP + gs] = key;
            }
        }
    }
    __syncthreads();

    // Phase B: one global reservation per gt, all 32 issued in parallel
    if (tid < JG) {
        int c = min(cnt_lds[tid], PCAP);
        int bas = 0;
        if (c > 0) bas = atomicAdd(&cnt2[jbase + tid], c);
        base_lds[tid] = bas;
    }
    __syncthreads();

    // Phase C: flush LDS pools to global
    for (int j = 0; j < JG; j++) {
        int c = min(cnt_lds[j], PCAP);
        int bas = base_lds[j];
        for (int t = tid; t < c; t += 256) {
            int dst = bas + t;
            if (dst < CAP) cand[(size_t)(jbase + j) * CAP + dst] = pool[j][t];
        }
    }
}

// ---------------- Kernel 2: per-(b,gt) wave top-13 + scatter -----------------
__global__ __launch_bounds__(256) void k_pick(
    const int* __restrict__ cnt2, const unsigned long long* __restrict__ cand,
    int* __restrict__ cnt, int* __restrict__ minj) {
    int lane = threadIdx.x & 63;
    int wave = threadIdx.x >> 6;
    int bj = blockIdx.x * 4 + wave;
    int b = bj >> 6, j = bj & 63;

    int n = min(cnt2[bj], CAP);
    if (n == 0) return;                                // wave-uniform

    const unsigned long long* L = cand + (size_t)bj * CAP;
    unsigned long long k0[CAP / 64];
    #pragma unroll
    for (int t = 0; t < CAP / 64; t++) {
        int i = t * 64 + lane;
        k0[t] = (i < n) ? L[i] : 0ULL;                 // 0 = empty (real keys nonzero)
    }

    unsigned int wanchor[TK];
    int P = 0;
    #pragma unroll
    for (int r = 0; r < TK; r++) {
        unsigned long long best = 0;
        #pragma unroll
        for (int t = 0; t < CAP / 64; t++) best = (k0[t] > best) ? k0[t] : best;
        for (int s = 1; s < 64; s <<= 1) {
            unsigned long long o = shfl_xor_u64(best, s);
            if (o > best) best = o;
        }
        if (!(best >> 32)) break;                      // out of positive metrics
        unsigned int aw = ~(unsigned int)(best & 0xFFFFFFFFull);
        wanchor[r] = aw;
        if (lane == 0) {
            atomicAdd(&cnt[b * A_N + (int)aw], 1);
            atomicMin(&minj[b * A_N + (int)aw], j);
        }
        #pragma unroll
        for (int t = 0; t < CAP / 64; t++) if (k0[t] == best) k0[t] = 0;
        P++;
    }

    // Fillers: top_k back-fills (13-P) lowest-index zero-metric anchors of the
    // full array; only in-box ones (all present as zero-metric candidates)
    // survive mask_in_gts. a is a filler iff a - |{positive winners < a}| < 13-P.
    if (P < TK) {
        int K = TK - P;
        #pragma unroll
        for (int t = 0; t < CAP / 64; t++) {
            unsigned long long key = k0[t];
            if (key != 0 && !(key >> 32)) {
                unsigned int a0 = ~(unsigned int)(key & 0xFFFFFFFFull);
                int off = 0;
                #pragma unroll
                for (int r = 0; r < TK; r++)
                    if (r < P && wanchor[r] < a0) off++;
                if ((int)a0 < K + off) {
                    atomicAdd(&cnt[b * A_N + (int)a0], 1);
                    atomicMin(&minj[b * A_N + (int)a0], j);
                }
            }
        }
    }
}

// ---------------- Kernel 3: per-anchor assignment + labels/bboxes/fg ---------
__global__ __launch_bounds__(256) void k_assign(
    const float* __restrict__ pd_scores, const float* __restrict__ pd_bboxes,
    const float* __restrict__ gt_bboxes, const int* __restrict__ gl_raw,
    const int* __restrict__ flag,
    const int* __restrict__ cnt, const int* __restrict__ minj,
    int* __restrict__ info, float* __restrict__ alignArr,
    unsigned int* posA, unsigned int* posO, float* __restrict__ out) {
    int i = blockIdx.x * 256 + threadIdx.x;
    if (i >= BS * A_N) return;
    int b = i / A_N;
    int c = cnt[i];
    int f64 = *flag;

    float4 p = ((const float4*)pd_bboxes)[i];
    int jstar = 0;
    if (c == 1) {
        jstar = minj[i];
    } else if (c > 1) {
        float bv = -1.f; int bj_ = 0;
        const float4* gb = (const float4*)(gt_bboxes + (size_t)b * NGT * 4);
        for (int j = 0; j < NGT; j++) {
            float4 g = gb[j];
            float ov = iou_f(g.x, g.y, g.z, g.w, p.x, p.y, p.z, p.w);
            if (ov > bv) { bv = ov; bj_ = j; }
        }
        jstar = bj_;
    }

    int lbl = get_gl(gl_raw, f64, b * NGT + jstar);
    if (lbl < 0) lbl = 0;

    out[OFF_LB + i] = (float)lbl;
    float4 g = ((const float4*)gt_bboxes)[b * NGT + jstar];
    ((float4*)(out + OFF_BB))[i] = g;

    int fg = (c > 0) ? 1 : 0;
    out[OFF_FG + i] = (float)fg;

    float al = 0.f;
    if (fg) {
        float ov = iou_f(g.x, g.y, g.z, g.w, p.x, p.y, p.z, p.w);
        float s  = pd_scores[(size_t)i * NC + lbl];
        al = s * powf(ov, 6.0f);
        atomicMax((int*)&posA[b * NGT + jstar], __float_as_int(al));
        atomicMax((int*)&posO[b * NGT + jstar], __float_as_int(ov));
    }
    alignArr[i] = al;
    info[i] = jstar | (lbl << 8) | (fg << 16);
}

// ---------------- Kernel 4: write the 86 MB target_scores (nontemporal f4) ---
__global__ __launch_bounds__(256) void k_scores(
    const int* __restrict__ info, const float* __restrict__ alignArr,
    const unsigned int* __restrict__ posA, const unsigned int* __restrict__ posO,
    float* __restrict__ out) {
    int t = blockIdx.x * 256 + threadIdx.x;
    const int TOT = BS * A_N * (NC / 4);
    if (t >= TOT) return;
    int anchor = t / (NC / 4);
    int q = t - anchor * (NC / 4);
    int inf = info[anchor];
    nt4 v = (nt4)(0.f);
    if (inf & (1 << 16)) {
        int lbl = (inf >> 8) & 255;
        int c0 = q * 4;
        if (lbl >= c0 && lbl < c0 + 4) {
            int jstar = inf & 255;
            int b = anchor / A_N;
            float pa = __int_as_float((int)posA[b * NGT + jstar]);
            float po = __int_as_float((int)posO[b * NGT + jstar]);
            float norm = alignArr[anchor] * po / (pa + EPSF);
            v[lbl - c0] = norm;
        }
    }
    __builtin_nontemporal_store(v, &((nt4*)(out + OFF_SC))[t]);
}

extern "C" void kernel_launch(void* const* d_in, const int* in_sizes, int n_in,
                              void* d_out, int out_size, void* d_ws, size_t ws_size,
                              hipStream_t stream) {
    const float* pd_scores = (const float*)d_in[0];
    const float* pd_bboxes = (const float*)d_in[1];
    const float* anc       = (const float*)d_in[2];
    const int*   gl_raw    = (const int*)d_in[3];
    const float* gt_bboxes = (const float*)d_in[4];
    const float* mask_gt   = (const float*)d_in[5];
    float* out = (float*)d_out;

    char* ws = (char*)d_ws;
    int*                flag     = (int*)(ws + WS_FLAG);
    int*                cnt      = (int*)(ws + WS_CNT);
    int*                minj     = (int*)(ws + WS_MINJ);
    int*                info     = (int*)(ws + WS_INFO);
    float*              alignArr = (float*)(ws + WS_ALIGN);
    unsigned int*       posA     = (unsigned int*)(ws + WS_POSA);
    unsigned int*       posO     = (unsigned int*)(ws + WS_POSO);
    int*                cnt2     = (int*)(ws + WS_CNT2);
    unsigned long long* cand     = (unsigned long long*)(ws + WS_CAND);

    k_init<<<(BS * A_N + 255) / 256, 256, 0, stream>>>(cnt, minj, posA, posO, cnt2, flag, gl_raw);
    k_cand<<<BS * NTILE * NJG, 256, 0, stream>>>(pd_scores, pd_bboxes, anc, gl_raw,
                                                 gt_bboxes, mask_gt, flag, cnt2, cand);
    k_pick<<<BS * NGT / 4, 256, 0, stream>>>(cnt2, cand, cnt, minj);
    k_assign<<<(BS * A_N + 255) / 256, 256, 0, stream>>>(pd_scores, pd_bboxes, gt_bboxes,
                                                         gl_raw, flag, cnt, minj,
                                                         info, alignArr, posA, posO, out);
    k_scores<<<(BS * A_N * (NC / 4) + 255) / 256, 256, 0, stream>>>(info, alignArr,
                                                                    posA, posO, out);
}

// Round 5
// 215.694 us; speedup vs baseline: 1.4477x; 1.0076x over previous
//
#include <hip/hip_runtime.h>
#include <math.h>

// Problem constants
#define A_N   8400
#define BS    32
#define NGT   64
#define NC    80
#define TK    13
#define EPSF  1e-9f
#define CAP   1024          // dense per-(b,gt) candidate list capacity
#define JG    32            // gts per k_cand block (64 split in 2 groups)
#define NJG   2
#define NTILE 33            // ceil(8400/256)
#define PCAP  64            // LDS pool capacity per (block, gt)
#define NCAND (BS * NTILE * NJG)   // 2112 k_cand blocks

typedef float nt4 __attribute__((ext_vector_type(4)));   // native vec for nontemporal store

// Output layout (floats), concatenated in reference return order
#define OFF_LB 0
#define OFF_BB (BS * A_N)
#define OFF_SC (OFF_BB + BS * A_N * 4)
#define OFF_FG (OFF_SC + BS * A_N * NC)

// Workspace layout (byte offsets, all 256-aligned)
#define WS_FLAG   0
#define WS_CNT    256
#define WS_MINJ   (WS_CNT   + BS * A_N * 4)
#define WS_INFO   (WS_MINJ  + BS * A_N * 4)
#define WS_ALIGN  (WS_INFO  + BS * A_N * 4)
#define WS_POSA   (WS_ALIGN + BS * A_N * 4)
#define WS_POSO   (WS_POSA  + BS * NGT * 4)
#define WS_CNT2   (WS_POSO  + BS * NGT * 4)
#define WS_CAND   (WS_CNT2  + BS * NGT * 4)
// cand: 2048 * CAP * 8 = 16.78 MB ; total ~= 21.1 MB

__device__ __forceinline__ float iou_f(float g0, float g1, float g2, float g3,
                                       float p0, float p1, float p2, float p3) {
    float ltx = fmaxf(g0, p0), lty = fmaxf(g1, p1);
    float rbx = fminf(g2, p2), rby = fminf(g3, p3);
    float ov  = fmaxf(rbx - ltx, 0.f) * fmaxf(rby - lty, 0.f);
    float a1  = fmaxf(g2 - g0, 0.f) * fmaxf(g3 - g1, 0.f);
    float a2  = fmaxf(p2 - p0, 0.f) * fmaxf(p3 - p1, 0.f);
    return ov / (a1 + a2 - ov + EPSF);
}

__device__ __forceinline__ int get_gl(const int* g, int flag64, int i) {
    return flag64 ? g[2 * i] : g[i];
}

__device__ __forceinline__ unsigned long long shfl_xor_u64(unsigned long long x, int m) {
    int lo = __shfl_xor((int)(unsigned int)(x & 0xFFFFFFFFull), m, 64);
    int hi = __shfl_xor((int)(unsigned int)(x >> 32), m, 64);
    return ((unsigned long long)(unsigned int)hi << 32) | (unsigned int)lo;
}

// ---------------- Kernel 0: init small counters + detect gt_labels stride ----
__global__ __launch_bounds__(256) void k_init(unsigned int* posA, unsigned int* posO,
                                              int* cnt2, int* flag, const int* gl_raw) {
    int i = blockIdx.x * 256 + threadIdx.x;
    if (i < BS * NGT) { posA[i] = 0u; posO[i] = 0u; cnt2[i] = 0; }
    if (i == 0) {
        int f = 1;
        for (int k = 0; k < 64; k++) {
            if (gl_raw[2 * k + 1] != 0) { f = 0; break; }
        }
        *flag = f;
    }
}

// ---------------- Kernel 1: dense in-box sweep -> candidate lists ------------
// Also absorbs: 86 MB zero-fill of the target_scores region (nontemporal,
// grid-stride — pure store-BW, co-scheduled with the latency-bound hit loop)
// and the cnt/minj zeroing (consumed only by k_pick, next in stream).
__global__ __launch_bounds__(256) void k_cand(
    const float* __restrict__ pd_scores, const float* __restrict__ pd_bboxes,
    const float* __restrict__ anc, const int* __restrict__ gl_raw,
    const float* __restrict__ gt_bboxes, const float* __restrict__ mask_gt,
    const int* __restrict__ flag,
    int* __restrict__ cnt2, unsigned long long* __restrict__ cand,
    int* __restrict__ cnt, int* __restrict__ minj, float* __restrict__ out) {
    __shared__ float4 sgt[JG];
    __shared__ int    slbl[JG];
    __shared__ int    smask[JG];
    __shared__ int    cnt_lds[JG];
    __shared__ int    base_lds[JG];
    __shared__ unsigned long long pool[JG][PCAP];

    int bid  = blockIdx.x;
    int b    = bid / (NTILE * NJG);
    int rem  = bid % (NTILE * NJG);
    int tile = rem / NJG;
    int jg   = rem % NJG;
    int tid  = threadIdx.x;
    int a    = tile * 256 + tid;
    int jbase = b * NGT + jg * JG;

    if (tid < JG) {
        sgt[tid]   = ((const float4*)gt_bboxes)[jbase + tid];
        slbl[tid]  = get_gl(gl_raw, *flag, jbase + tid);
        smask[tid] = (mask_gt[jbase + tid] != 0.f);
        cnt_lds[tid] = 0;
    }

    // Absorbed zero-fills (independent store traffic, no barrier needed yet)
    {
        int gth = bid * 256 + tid;
        const int GS = NCAND * 256;
        nt4* scz = (nt4*)(out + OFF_SC);
        for (int t = gth; t < BS * A_N * (NC / 4); t += GS)
            __builtin_nontemporal_store((nt4)(0.f), &scz[t]);
        for (int t = gth; t < BS * A_N; t += GS) {
            cnt[t] = 0; minj[t] = 1 << 30;
        }
    }
    __syncthreads();

    bool act = (a < A_N);
    float2 an = make_float2(0.f, 0.f);
    float4 p  = make_float4(0.f, 0.f, 0.f, 0.f);
    const float* sc = pd_scores;
    if (act) {
        an = ((const float2*)anc)[a];
        p  = ((const float4*)pd_bboxes)[(size_t)b * A_N + a];
        sc = pd_scores + (size_t)b * A_N * NC + (size_t)a * NC;
    }

    // Phase A: hit detection + LDS append
    for (int j = 0; j < JG; j++) {
        if (!smask[j]) continue;                       // block-uniform
        if (!act) continue;
        float4 g = sgt[j];
        float d = fminf(fminf(an.x - g.x, an.y - g.y),
                        fminf(g.z - an.x, g.w - an.y));
        if (d > EPSF) {
            float iou = iou_f(g.x, g.y, g.z, g.w, p.x, p.y, p.z, p.w);
            float m = 0.f;
            if (iou > 0.f) {
                float s = sc[slbl[j]];
                m = s * powf(iou, 6.0f);               // identical op order (absmax 0.0)
            }
            unsigned long long key =
                ((unsigned long long)__float_as_uint(m) << 32) |
                (unsigned int)(~(unsigned int)a);      // (metric desc, anchor asc) under max
            int slot = atomicAdd(&cnt_lds[j], 1);      // LDS atomic
            if (slot < PCAP) {
                pool[j][slot] = key;
            } else {                                   // rare overflow: direct global
                int gs = atomicAdd(&cnt2[jbase + j], 1);
                if (gs < CAP) cand[(size_t)(jbase + j) * CAP + gs] = key;
            }
        }
    }
    __syncthreads();

    // Phase B: one global reservation per gt, all 32 issued in parallel
    if (tid < JG) {
        int c = min(cnt_lds[tid], PCAP);
        int bas = 0;
        if (c > 0) bas = atomicAdd(&cnt2[jbase + tid], c);
        base_lds[tid] = bas;
    }
    __syncthreads();

    // Phase C: flush LDS pools to global
    for (int j = 0; j < JG; j++) {
        int c = min(cnt_lds[j], PCAP);
        int bas = base_lds[j];
        for (int t = tid; t < c; t += 256) {
            int dst = bas + t;
            if (dst < CAP) cand[(size_t)(jbase + j) * CAP + dst] = pool[j][t];
        }
    }
}

// ---------------- Kernel 2: per-(b,gt) wave top-13 + scatter -----------------
__global__ __launch_bounds__(256) void k_pick(
    const int* __restrict__ cnt2, const unsigned long long* __restrict__ cand,
    int* __restrict__ cnt, int* __restrict__ minj) {
    int lane = threadIdx.x & 63;
    int wave = threadIdx.x >> 6;
    int bj = blockIdx.x * 4 + wave;
    int b = bj >> 6, j = bj & 63;

    int n = min(cnt2[bj], CAP);
    if (n == 0) return;                                // wave-uniform

    const unsigned long long* L = cand + (size_t)bj * CAP;
    unsigned long long k0[CAP / 64];
    #pragma unroll
    for (int t = 0; t < CAP / 64; t++) {
        int i = t * 64 + lane;
        k0[t] = (i < n) ? L[i] : 0ULL;                 // 0 = empty (real keys nonzero)
    }

    unsigned int wanchor[TK];
    int P = 0;
    #pragma unroll
    for (int r = 0; r < TK; r++) {
        unsigned long long best = 0;
        #pragma unroll
        for (int t = 0; t < CAP / 64; t++) best = (k0[t] > best) ? k0[t] : best;
        for (int s = 1; s < 64; s <<= 1) {
            unsigned long long o = shfl_xor_u64(best, s);
            if (o > best) best = o;
        }
        if (!(best >> 32)) break;                      // out of positive metrics
        unsigned int aw = ~(unsigned int)(best & 0xFFFFFFFFull);
        wanchor[r] = aw;
        if (lane == 0) {
            atomicAdd(&cnt[b * A_N + (int)aw], 1);
            atomicMin(&minj[b * A_N + (int)aw], j);
        }
        #pragma unroll
        for (int t = 0; t < CAP / 64; t++) if (k0[t] == best) k0[t] = 0;
        P++;
    }

    // Fillers: top_k back-fills (13-P) lowest-index zero-metric anchors of the
    // full array; only in-box ones (all present as zero-metric candidates)
    // survive mask_in_gts. a is a filler iff a - |{positive winners < a}| < 13-P.
    if (P < TK) {
        int K = TK - P;
        #pragma unroll
        for (int t = 0; t < CAP / 64; t++) {
            unsigned long long key = k0[t];
            if (key != 0 && !(key >> 32)) {
                unsigned int a0 = ~(unsigned int)(key & 0xFFFFFFFFull);
                int off = 0;
                #pragma unroll
                for (int r = 0; r < TK; r++)
                    if (r < P && wanchor[r] < a0) off++;
                if ((int)a0 < K + off) {
                    atomicAdd(&cnt[b * A_N + (int)a0], 1);
                    atomicMin(&minj[b * A_N + (int)a0], j);
                }
            }
        }
    }
}

// ---------------- Kernel 3: per-anchor assignment + labels/bboxes/fg ---------
__global__ __launch_bounds__(256) void k_assign(
    const float* __restrict__ pd_scores, const float* __restrict__ pd_bboxes,
    const float* __restrict__ gt_bboxes, const int* __restrict__ gl_raw,
    const int* __restrict__ flag,
    const int* __restrict__ cnt, const int* __restrict__ minj,
    int* __restrict__ info, float* __restrict__ alignArr,
    unsigned int* posA, unsigned int* posO, float* __restrict__ out) {
    int i = blockIdx.x * 256 + threadIdx.x;
    if (i >= BS * A_N) return;
    int b = i / A_N;
    int c = cnt[i];
    int f64 = *flag;

    float4 p = ((const float4*)pd_bboxes)[i];
    int jstar = 0;
    if (c == 1) {
        jstar = minj[i];
    } else if (c > 1) {
        float bv = -1.f; int bj_ = 0;
        const float4* gb = (const float4*)(gt_bboxes + (size_t)b * NGT * 4);
        for (int j = 0; j < NGT; j++) {
            float4 g = gb[j];
            float ov = iou_f(g.x, g.y, g.z, g.w, p.x, p.y, p.z, p.w);
            if (ov > bv) { bv = ov; bj_ = j; }
        }
        jstar = bj_;
    }

    int lbl = get_gl(gl_raw, f64, b * NGT + jstar);
    if (lbl < 0) lbl = 0;

    out[OFF_LB + i] = (float)lbl;
    float4 g = ((const float4*)gt_bboxes)[b * NGT + jstar];
    ((float4*)(out + OFF_BB))[i] = g;

    int fg = (c > 0) ? 1 : 0;
    out[OFF_FG + i] = (float)fg;

    float al = 0.f;
    if (fg) {
        float ov = iou_f(g.x, g.y, g.z, g.w, p.x, p.y, p.z, p.w);
        float s  = pd_scores[(size_t)i * NC + lbl];
        al = s * powf(ov, 6.0f);
        atomicMax((int*)&posA[b * NGT + jstar], __float_as_int(al));
        atomicMax((int*)&posO[b * NGT + jstar], __float_as_int(ov));
    }
    alignArr[i] = al;
    info[i] = jstar | (lbl << 8) | (fg << 16);
}

// ---------------- Kernel 4: sparse norm scatter (fg anchors only) ------------
__global__ __launch_bounds__(256) void k_norm(
    const int* __restrict__ info, const float* __restrict__ alignArr,
    const unsigned int* __restrict__ posA, const unsigned int* __restrict__ posO,
    float* __restrict__ out) {
    int i = blockIdx.x * 256 + threadIdx.x;
    if (i >= BS * A_N) return;
    int inf = info[i];
    if (!(inf & (1 << 16))) return;        // background: zero-fill already done in k_cand
    int jstar = inf & 255;
    int lbl   = (inf >> 8) & 255;
    int b = i / A_N;
    float pa = __int_as_float((int)posA[b * NGT + jstar]);
    float po = __int_as_float((int)posO[b * NGT + jstar]);
    out[OFF_SC + (size_t)i * NC + lbl] = alignArr[i] * po / (pa + EPSF);
}

extern "C" void kernel_launch(void* const* d_in, const int* in_sizes, int n_in,
                              void* d_out, int out_size, void* d_ws, size_t ws_size,
                              hipStream_t stream) {
    const float* pd_scores = (const float*)d_in[0];
    const float* pd_bboxes = (const float*)d_in[1];
    const float* anc       = (const float*)d_in[2];
    const int*   gl_raw    = (const int*)d_in[3];
    const float* gt_bboxes = (const float*)d_in[4];
    const float* mask_gt   = (const float*)d_in[5];
    float* out = (float*)d_out;

    char* ws = (char*)d_ws;
    int*                flag     = (int*)(ws + WS_FLAG);
    int*                cnt      = (int*)(ws + WS_CNT);
    int*                minj     = (int*)(ws + WS_MINJ);
    int*                info     = (int*)(ws + WS_INFO);
    float*              alignArr = (float*)(ws + WS_ALIGN);
    unsigned int*       posA     = (unsigned int*)(ws + WS_POSA);
    unsigned int*       posO     = (unsigned int*)(ws + WS_POSO);
    int*                cnt2     = (int*)(ws + WS_CNT2);
    unsigned long long* cand     = (unsigned long long*)(ws + WS_CAND);

    k_init<<<8, 256, 0, stream>>>(posA, posO, cnt2, flag, gl_raw);
    k_cand<<<NCAND, 256, 0, stream>>>(pd_scores, pd_bboxes, anc, gl_raw,
                                      gt_bboxes, mask_gt, flag, cnt2, cand,
                                      cnt, minj, out);
    k_pick<<<BS * NGT / 4, 256, 0, stream>>>(cnt2, cand, cnt, minj);
    k_assign<<<(BS * A_N + 255) / 256, 256, 0, stream>>>(pd_scores, pd_bboxes, gt_bboxes,
                                                         gl_raw, flag, cnt, minj,
                                                         info, alignArr, posA, posO, out);
    k_norm<<<(BS * A_N + 255) / 256, 256, 0, stream>>>(info, alignArr, posA, posO, out);
}

// Round 6
// 210.309 us; speedup vs baseline: 1.4848x; 1.0256x over previous
//
#include <hip/hip_runtime.h>
#include <math.h>

// Problem constants
#define A_N   8400
#define BS    32
#define NGT   64
#define NC    80
#define TK    13
#define EPSF  1e-9f
#define CAP   1024          // dense per-(b,gt) candidate list capacity
#define JG    32            // gts per k_cand block (64 split in 2 groups)
#define NJG   2
#define NTILE 33            // ceil(8400/256)
#define PCAP  64            // LDS pool capacity per (block, gt)
#define NCAND (BS * NTILE * NJG)   // 2112 k_cand blocks

typedef float nt4 __attribute__((ext_vector_type(4)));   // native vec for nontemporal store

// Output layout (floats), concatenated in reference return order
#define OFF_LB 0
#define OFF_BB (BS * A_N)
#define OFF_SC (OFF_BB + BS * A_N * 4)
#define OFF_FG (OFF_SC + BS * A_N * NC)

// Workspace layout (byte offsets, all 256-aligned)
#define WS_FLAG   0
#define WS_CNT    256
#define WS_MINJ   (WS_CNT   + BS * A_N * 4)
#define WS_INFO   (WS_MINJ  + BS * A_N * 4)
#define WS_ALIGN  (WS_INFO  + BS * A_N * 4)
#define WS_POSA   (WS_ALIGN + BS * A_N * 4)
#define WS_POSO   (WS_POSA  + BS * NGT * 4)
#define WS_CNT2   (WS_POSO  + BS * NGT * 4)
#define WS_CAND   (WS_CNT2  + BS * NGT * 4)
// cand: 2048 * CAP * 8 = 16.78 MB ; total ~= 21.1 MB

__device__ __forceinline__ float iou_f(float g0, float g1, float g2, float g3,
                                       float p0, float p1, float p2, float p3) {
    float ltx = fmaxf(g0, p0), lty = fmaxf(g1, p1);
    float rbx = fminf(g2, p2), rby = fminf(g3, p3);
    float ov  = fmaxf(rbx - ltx, 0.f) * fmaxf(rby - lty, 0.f);
    float a1  = fmaxf(g2 - g0, 0.f) * fmaxf(g3 - g1, 0.f);
    float a2  = fmaxf(p2 - p0, 0.f) * fmaxf(p3 - p1, 0.f);
    return ov / (a1 + a2 - ov + EPSF);
}

__device__ __forceinline__ int get_gl(const int* g, int flag64, int i) {
    return flag64 ? g[2 * i] : g[i];
}

__device__ __forceinline__ unsigned long long shfl_xor_u64(unsigned long long x, int m) {
    int lo = __shfl_xor((int)(unsigned int)(x & 0xFFFFFFFFull), m, 64);
    int hi = __shfl_xor((int)(unsigned int)(x >> 32), m, 64);
    return ((unsigned long long)(unsigned int)hi << 32) | (unsigned int)lo;
}

// ---------------- Kernel 0: init small counters + detect gt_labels stride ----
__global__ __launch_bounds__(256) void k_init(unsigned int* posA, unsigned int* posO,
                                              int* cnt2, int* flag, const int* gl_raw) {
    int i = blockIdx.x * 256 + threadIdx.x;
    if (i < BS * NGT) { posA[i] = 0u; posO[i] = 0u; cnt2[i] = 0; }
    if (i == 0) {
        int f = 1;
        for (int k = 0; k < 64; k++) {
            if (gl_raw[2 * k + 1] != 0) { f = 0; break; }
        }
        *flag = f;
    }
}

// ---------------- Kernel 1: dense in-box sweep -> candidate lists ------------
// Absorbed zero-fills (86 MB target_scores + cnt/minj) run at the END, after
// the last barrier: stores drain only at kernel retire, overlapping other
// blocks' latency-bound hit loops (R5's pre-barrier placement serialized them
// via the barrier's vmcnt(0) drain).
__global__ __launch_bounds__(256) void k_cand(
    const float* __restrict__ pd_scores, const float* __restrict__ pd_bboxes,
    const float* __restrict__ anc, const int* __restrict__ gl_raw,
    const float* __restrict__ gt_bboxes, const float* __restrict__ mask_gt,
    const int* __restrict__ flag,
    int* __restrict__ cnt2, unsigned long long* __restrict__ cand,
    int* __restrict__ cnt, int* __restrict__ minj, float* __restrict__ out) {
    __shared__ float4 sgt[JG];
    __shared__ int    slbl[JG];
    __shared__ int    smask[JG];
    __shared__ int    cnt_lds[JG];
    __shared__ int    base_lds[JG];
    __shared__ unsigned long long pool[JG][PCAP];

    int bid  = blockIdx.x;
    int b    = bid / (NTILE * NJG);
    int rem  = bid % (NTILE * NJG);
    int tile = rem / NJG;
    int jg   = rem % NJG;
    int tid  = threadIdx.x;
    int a    = tile * 256 + tid;
    int jbase = b * NGT + jg * JG;

    if (tid < JG) {
        sgt[tid]   = ((const float4*)gt_bboxes)[jbase + tid];
        slbl[tid]  = get_gl(gl_raw, *flag, jbase + tid);
        smask[tid] = (mask_gt[jbase + tid] != 0.f);
        cnt_lds[tid] = 0;
    }
    __syncthreads();

    bool act = (a < A_N);
    float2 an = make_float2(0.f, 0.f);
    float4 p  = make_float4(0.f, 0.f, 0.f, 0.f);
    const float* sc = pd_scores;
    if (act) {
        an = ((const float2*)anc)[a];
        p  = ((const float4*)pd_bboxes)[(size_t)b * A_N + a];
        sc = pd_scores + (size_t)b * A_N * NC + (size_t)a * NC;
    }

    // Phase A: hit detection + LDS append
    for (int j = 0; j < JG; j++) {
        if (!smask[j]) continue;                       // block-uniform
        if (!act) continue;
        float4 g = sgt[j];
        float d = fminf(fminf(an.x - g.x, an.y - g.y),
                        fminf(g.z - an.x, g.w - an.y));
        if (d > EPSF) {
            float iou = iou_f(g.x, g.y, g.z, g.w, p.x, p.y, p.z, p.w);
            float m = 0.f;
            if (iou > 0.f) {
                float s = sc[slbl[j]];
                m = s * powf(iou, 6.0f);               // identical op order (absmax 0.0)
            }
            unsigned long long key =
                ((unsigned long long)__float_as_uint(m) << 32) |
                (unsigned int)(~(unsigned int)a);      // (metric desc, anchor asc) under max
            int slot = atomicAdd(&cnt_lds[j], 1);      // LDS atomic
            if (slot < PCAP) {
                pool[j][slot] = key;
            } else {                                   // rare overflow: direct global
                int gs = atomicAdd(&cnt2[jbase + j], 1);
                if (gs < CAP) cand[(size_t)(jbase + j) * CAP + gs] = key;
            }
        }
    }
    __syncthreads();

    // Phase B: one global reservation per gt, all 32 issued in parallel
    if (tid < JG) {
        int c = min(cnt_lds[tid], PCAP);
        int bas = 0;
        if (c > 0) bas = atomicAdd(&cnt2[jbase + tid], c);
        base_lds[tid] = bas;
    }
    __syncthreads();

    // Phase C: flush LDS pools to global
    for (int j = 0; j < JG; j++) {
        int c = min(cnt_lds[j], PCAP);
        int bas = base_lds[j];
        for (int t = tid; t < c; t += 256) {
            int dst = bas + t;
            if (dst < CAP) cand[(size_t)(jbase + j) * CAP + dst] = pool[j][t];
        }
    }

    // Phase D (post-barrier): absorbed zero-fills; drain at kernel retire only
    {
        int gth = bid * 256 + tid;
        const int GS = NCAND * 256;
        nt4* scz = (nt4*)(out + OFF_SC);
        for (int t = gth; t < BS * A_N * (NC / 4); t += GS)
            __builtin_nontemporal_store((nt4)(0.f), &scz[t]);
        for (int t = gth; t < BS * A_N; t += GS) {
            cnt[t] = 0; minj[t] = 1 << 30;
        }
    }
}

// ---------------- Kernel 2: per-(b,gt) wave top-13 + scatter -----------------
template <int NT>
__device__ __forceinline__ void pick_body(
    int lane, int b, int j, int n, const unsigned long long* __restrict__ L,
    int* __restrict__ cnt, int* __restrict__ minj) {
    unsigned long long k0[NT];
    #pragma unroll
    for (int t = 0; t < NT; t++) {
        int i = t * 64 + lane;
        k0[t] = (i < n) ? L[i] : 0ULL;                 // 0 = empty (real keys nonzero)
    }

    unsigned int wanchor[TK];
    int P = 0;
    #pragma unroll
    for (int r = 0; r < TK; r++) {
        unsigned long long best = 0;
        #pragma unroll
        for (int t = 0; t < NT; t++) best = (k0[t] > best) ? k0[t] : best;
        for (int s = 1; s < 64; s <<= 1) {
            unsigned long long o = shfl_xor_u64(best, s);
            if (o > best) best = o;
        }
        if (!(best >> 32)) break;                      // out of positive metrics
        unsigned int aw = ~(unsigned int)(best & 0xFFFFFFFFull);
        wanchor[r] = aw;
        if (lane == 0) {
            atomicAdd(&cnt[b * A_N + (int)aw], 1);
            atomicMin(&minj[b * A_N + (int)aw], j);
        }
        #pragma unroll
        for (int t = 0; t < NT; t++) if (k0[t] == best) k0[t] = 0;
        P++;
    }

    // Fillers: top_k back-fills (13-P) lowest-index zero-metric anchors of the
    // full array; only in-box ones (all present as zero-metric candidates)
    // survive mask_in_gts. a is a filler iff a - |{positive winners < a}| < 13-P.
    if (P < TK) {
        int K = TK - P;
        #pragma unroll
        for (int t = 0; t < NT; t++) {
            unsigned long long key = k0[t];
            if (key != 0 && !(key >> 32)) {
                unsigned int a0 = ~(unsigned int)(key & 0xFFFFFFFFull);
                int off = 0;
                #pragma unroll
                for (int r = 0; r < TK; r++)
                    if (r < P && wanchor[r] < a0) off++;
                if ((int)a0 < K + off) {
                    atomicAdd(&cnt[b * A_N + (int)a0], 1);
                    atomicMin(&minj[b * A_N + (int)a0], j);
                }
            }
        }
    }
}

__global__ __launch_bounds__(256) void k_pick(
    const int* __restrict__ cnt2, const unsigned long long* __restrict__ cand,
    int* __restrict__ cnt, int* __restrict__ minj) {
    int lane = threadIdx.x & 63;
    int wave = threadIdx.x >> 6;
    int bj = blockIdx.x * 4 + wave;
    int b = bj >> 6, j = bj & 63;

    int n = min(cnt2[bj], CAP);
    if (n == 0) return;                                // wave-uniform
    const unsigned long long* L = cand + (size_t)bj * CAP;

    // wave-uniform tier dispatch: compile-time bounds keep k0[] in registers
    if (n <= 128)      pick_body<2>(lane, b, j, n, L, cnt, minj);
    else if (n <= 320) pick_body<5>(lane, b, j, n, L, cnt, minj);
    else               pick_body<16>(lane, b, j, n, L, cnt, minj);
}

// ---------------- Kernel 3: per-anchor assignment + labels/bboxes/fg ---------
__global__ __launch_bounds__(256) void k_assign(
    const float* __restrict__ pd_scores, const float* __restrict__ pd_bboxes,
    const float* __restrict__ gt_bboxes, const int* __restrict__ gl_raw,
    const int* __restrict__ flag,
    const int* __restrict__ cnt, const int* __restrict__ minj,
    int* __restrict__ info, float* __restrict__ alignArr,
    unsigned int* posA, unsigned int* posO, float* __restrict__ out) {
    int i = blockIdx.x * 256 + threadIdx.x;
    if (i >= BS * A_N) return;
    int b = i / A_N;
    int c = cnt[i];
    int f64 = *flag;

    float4 p = ((const float4*)pd_bboxes)[i];
    int jstar = 0;
    if (c == 1) {
        jstar = minj[i];
    } else if (c > 1) {
        float bv = -1.f; int bj_ = 0;
        const float4* gb = (const float4*)(gt_bboxes + (size_t)b * NGT * 4);
        for (int j = 0; j < NGT; j++) {
            float4 g = gb[j];
            float ov = iou_f(g.x, g.y, g.z, g.w, p.x, p.y, p.z, p.w);
            if (ov > bv) { bv = ov; bj_ = j; }
        }
        jstar = bj_;
    }

    int lbl = get_gl(gl_raw, f64, b * NGT + jstar);
    if (lbl < 0) lbl = 0;

    out[OFF_LB + i] = (float)lbl;
    float4 g = ((const float4*)gt_bboxes)[b * NGT + jstar];
    ((float4*)(out + OFF_BB))[i] = g;

    int fg = (c > 0) ? 1 : 0;
    out[OFF_FG + i] = (float)fg;

    float al = 0.f;
    if (fg) {
        float ov = iou_f(g.x, g.y, g.z, g.w, p.x, p.y, p.z, p.w);
        float s  = pd_scores[(size_t)i * NC + lbl];
        al = s * powf(ov, 6.0f);
        atomicMax((int*)&posA[b * NGT + jstar], __float_as_int(al));
        atomicMax((int*)&posO[b * NGT + jstar], __float_as_int(ov));
    }
    alignArr[i] = al;
    info[i] = jstar | (lbl << 8) | (fg << 16);
}

// ---------------- Kernel 4: sparse norm scatter (fg anchors only) ------------
__global__ __launch_bounds__(256) void k_norm(
    const int* __restrict__ info, const float* __restrict__ alignArr,
    const unsigned int* __restrict__ posA, const unsigned int* __restrict__ posO,
    float* __restrict__ out) {
    int i = blockIdx.x * 256 + threadIdx.x;
    if (i >= BS * A_N) return;
    int inf = info[i];
    if (!(inf & (1 << 16))) return;        // background: zero-fill already done in k_cand
    int jstar = inf & 255;
    int lbl   = (inf >> 8) & 255;
    int b = i / A_N;
    float pa = __int_as_float((int)posA[b * NGT + jstar]);
    float po = __int_as_float((int)posO[b * NGT + jstar]);
    out[OFF_SC + (size_t)i * NC + lbl] = alignArr[i] * po / (pa + EPSF);
}

extern "C" void kernel_launch(void* const* d_in, const int* in_sizes, int n_in,
                              void* d_out, int out_size, void* d_ws, size_t ws_size,
                              hipStream_t stream) {
    const float* pd_scores = (const float*)d_in[0];
    const float* pd_bboxes = (const float*)d_in[1];
    const float* anc       = (const float*)d_in[2];
    const int*   gl_raw    = (const int*)d_in[3];
    const float* gt_bboxes = (const float*)d_in[4];
    const float* mask_gt   = (const float*)d_in[5];
    float* out = (float*)d_out;

    char* ws = (char*)d_ws;
    int*                flag     = (int*)(ws + WS_FLAG);
    int*                cnt      = (int*)(ws + WS_CNT);
    int*                minj     = (int*)(ws + WS_MINJ);
    int*                info     = (int*)(ws + WS_INFO);
    float*              alignArr = (float*)(ws + WS_ALIGN);
    unsigned int*       posA     = (unsigned int*)(ws + WS_POSA);
    unsigned int*       posO     = (unsigned int*)(ws + WS_POSO);
    int*                cnt2     = (int*)(ws + WS_CNT2);
    unsigned long long* cand     = (unsigned long long*)(ws + WS_CAND);

    k_init<<<8, 256, 0, stream>>>(posA, posO, cnt2, flag, gl_raw);
    k_cand<<<NCAND, 256, 0, stream>>>(pd_scores, pd_bboxes, anc, gl_raw,
                                      gt_bboxes, mask_gt, flag, cnt2, cand,
                                      cnt, minj, out);
    k_pick<<<BS * NGT / 4, 256, 0, stream>>>(cnt2, cand, cnt, minj);
    k_assign<<<(BS * A_N + 255) / 256, 256, 0, stream>>>(pd_scores, pd_bboxes, gt_bboxes,
                                                         gl_raw, flag, cnt, minj,
                                                         info, alignArr, posA, posO, out);
    k_norm<<<(BS * A_N + 255) / 256, 256, 0, stream>>>(info, alignArr, posA, posO, out);
}